// Round 2
// baseline (1813.247 us; speedup 1.0000x reference)
//
#include <hip/hip_runtime.h>
#include <hip/hip_bf16.h>

// ---- problem constants ----
#define B_      64
#define HW_     56        // H == W == 56
#define C_      192
#define HEADS_  6
#define HD_     32
#define WS_     7
#define TOK_    49
#define NW_     64        // windows per image (8x8)
#define NWIN_   4096      // B_*NW_
#define M_      200704    // NWIN_*TOK_
#define C3_     576
#define HID_    768
#define SHIFT_  3

typedef unsigned short ushort_t;
typedef __bf16 bf16v8 __attribute__((ext_vector_type(8)));
typedef float  f32x4  __attribute__((ext_vector_type(4)));

__device__ inline float bf2f(ushort_t u) {
  union { unsigned int i; float f; } c; c.i = ((unsigned int)u) << 16; return c.f;
}
__device__ inline ushort_t f2bf(float f) {
  union { float f; unsigned int u; } c; c.f = f;
  unsigned int u = c.u;
  return (ushort_t)((u + 0x7fffu + ((u >> 16) & 1u)) >> 16);  // RNE
}
__device__ inline bf16v8 ld8(const ushort_t* p) { return *(const bf16v8*)p; }

// exact-GELU via Abramowitz-Stegun 7.1.26 erf (max err 1.5e-7), ~17 VALU ops
__device__ inline float gelu_f(float x) {
  float z = fabsf(x) * 0.70710678118654752f;
  float t = __builtin_amdgcn_rcpf(fmaf(0.3275911f, z, 1.0f));
  float p = fmaf(fmaf(fmaf(fmaf(1.061405429f, t, -1.453152027f), t,
                           1.421413741f), t, -0.284496736f), t, 0.254829592f);
  p *= t;
  float e = __expf(-z * z);
  float erfa = fmaf(-p, e, 1.0f);                     // erf(|z|) in [0,1)
  unsigned s = __float_as_uint(x) & 0x80000000u;
  float erfs = __uint_as_float(__float_as_uint(erfa) | s);
  return 0.5f * x * (1.0f + erfs);
}

// ---- fp32 -> bf16 weight convert (all 4 weights, one launch) ----
__global__ __launch_bounds__(256) void k_f2b4(const float* __restrict__ s0, ushort_t* __restrict__ d0, int n0,
                                              const float* __restrict__ s1, ushort_t* __restrict__ d1, int n1,
                                              const float* __restrict__ s2, ushort_t* __restrict__ d2, int n2,
                                              const float* __restrict__ s3, ushort_t* __restrict__ d3, int n3) {
  int i = blockIdx.x * 256 + threadIdx.x;
  if (i < n0) { d0[i] = f2bf(s0[i]); return; }
  i -= n0;
  if (i < n1) { d1[i] = f2bf(s1[i]); return; }
  i -= n1;
  if (i < n2) { d2[i] = f2bf(s2[i]); return; }
  i -= n2;
  if (i < n3) { d3[i] = f2bf(s3[i]); }
}

// ---- LN1 + roll(-3,-3) + window partition gather: x (B,H,W,C) -> xw bf16 (M,192) ----
__global__ __launch_bounds__(256) void k_ln1(const float* __restrict__ x,
                                             const float* __restrict__ g,
                                             const float* __restrict__ b,
                                             ushort_t* __restrict__ xw) {
  int wave = threadIdx.x >> 6, lane = threadIdx.x & 63;
  int gtok = blockIdx.x * 4 + wave;           // window-order token index
  int win = gtok / 49, tok = gtok - win * 49;
  int bb = win >> 6, nw = win & 63;
  int wr = nw >> 3, wc = nw & 7;
  int ii = tok / 7, jj = tok - ii * 7;
  int hh = wr * 7 + ii + SHIFT_; if (hh >= HW_) hh -= HW_;
  int ww = wc * 7 + jj + SHIFT_; if (ww >= HW_) ww -= HW_;
  const float* row = x + ((size_t)bb * 3136 + hh * 56 + ww) * C_;
  float vals[3]; float s = 0.f, s2 = 0.f;
  #pragma unroll
  for (int r = 0; r < 3; ++r) { float t = row[lane + 64 * r]; vals[r] = t; s += t; s2 += t * t; }
  #pragma unroll
  for (int o = 32; o; o >>= 1) { s += __shfl_xor(s, o); s2 += __shfl_xor(s2, o); }
  float mean = s * (1.f / 192.f);
  float var  = s2 * (1.f / 192.f) - mean * mean;
  float rstd = rsqrtf(var + 1e-5f);
  ushort_t* orow = xw + (size_t)gtok * C_;
  #pragma unroll
  for (int r = 0; r < 3; ++r) {
    int c = lane + 64 * r;
    orow[c] = f2bf((vals[r] - mean) * rstd * g[c] + b[c]);
  }
}

// ---- QKV GEMM: xw (M,192) @ wq^T (576,192) + bias -> q,k,v (nwin,heads,tok,hd) bf16 ----
__global__ __launch_bounds__(256) void k_qkv(const ushort_t* __restrict__ xw,
                                             const ushort_t* __restrict__ wq,
                                             const float* __restrict__ qkvb,
                                             ushort_t* __restrict__ q,
                                             ushort_t* __restrict__ k,
                                             ushort_t* __restrict__ v) {
  int wave = threadIdx.x >> 6, lane = threadIdx.x & 63;
  int lr = lane & 15, lk = (lane >> 4) * 8;
  int mbase = blockIdx.x * 128 + wave * 32;
  int nbase = blockIdx.y * 64;
  bf16v8 a[2][6];
  #pragma unroll
  for (int rt = 0; rt < 2; ++rt)
    #pragma unroll
    for (int kk = 0; kk < 6; ++kk)
      a[rt][kk] = ld8(xw + (size_t)(mbase + rt * 16 + lr) * C_ + kk * 32 + lk);
  for (int nt = 0; nt < 4; ++nt) {
    int ncol = nbase + nt * 16 + lr;          // D col = lane&15
    f32x4 acc0 = {0.f, 0.f, 0.f, 0.f}, acc1 = {0.f, 0.f, 0.f, 0.f};
    #pragma unroll
    for (int kk = 0; kk < 6; ++kk) {
      bf16v8 bb = ld8(wq + (size_t)ncol * C_ + kk * 32 + lk);
      acc0 = __builtin_amdgcn_mfma_f32_16x16x32_bf16(a[0][kk], bb, acc0, 0, 0, 0);
      acc1 = __builtin_amdgcn_mfma_f32_16x16x32_bf16(a[1][kk], bb, acc1, 0, 0, 0);
    }
    float bias = qkvb[ncol];
    int sec = ncol / 192, cm = ncol - sec * 192;
    int head = cm >> 5, dd = cm & 31;
    ushort_t* dst = sec == 0 ? q : (sec == 1 ? k : v);
    #pragma unroll
    for (int rt = 0; rt < 2; ++rt) {
      f32x4 acc = rt ? acc1 : acc0;
      #pragma unroll
      for (int i = 0; i < 4; ++i) {
        int gg = mbase + rt * 16 + (lane >> 4) * 4 + i;   // D row
        int win = gg / 49, tok = gg - win * 49;
        dst[((size_t)(win * 6 + head) * 49 + tok) * 32 + dd] = f2bf(acc[i] + bias);
      }
    }
  }
}

// ---- attention per (window, head) ----
__global__ __launch_bounds__(256) void k_attn(const ushort_t* __restrict__ q,
                                              const ushort_t* __restrict__ k,
                                              const ushort_t* __restrict__ v,
                                              const float* __restrict__ rpb,
                                              const int* __restrict__ relidx,
                                              const float* __restrict__ amask,
                                              ushort_t* __restrict__ aout) {
  __shared__ ushort_t qs[49 * 32];
  __shared__ ushort_t kst[32 * 52];   // transposed [d][kc], padded
  __shared__ ushort_t vs[49 * 32];
  __shared__ float S[49][52];
  int wh = blockIdx.x;
  int win = wh / 6, head = wh - win * 6;
  int nw = win & 63;
  const size_t base = (size_t)wh * (49 * 32);
  for (int idx = threadIdx.x; idx < 49 * 32; idx += 256) {
    int kc = idx >> 5, d = idx & 31;
    qs[idx] = q[base + idx];
    kst[d * 52 + kc] = k[base + idx];
    vs[idx] = v[base + idx];
  }
  __syncthreads();
  const float scale = 0.17677669529663687f;  // 1/sqrt(32)
  for (int p = threadIdx.x; p < 49 * 49; p += 256) {
    int qr = p / 49, kc = p - qr * 49;
    float acc = 0.f;
    #pragma unroll
    for (int d = 0; d < 32; ++d)
      acc += bf2f(qs[qr * 32 + d]) * bf2f(kst[d * 52 + kc]);
    float bias = rpb[relidx[p] * 6 + head];
    float mval = amask[(size_t)nw * (49 * 49) + p];
    S[qr][kc] = acc * scale + bias + mval;
  }
  __syncthreads();
  int wave = threadIdx.x >> 6, lane = threadIdx.x & 63;
  for (int r = wave; r < 49; r += 4) {
    float val = lane < 49 ? S[r][lane] : -1e30f;
    float mx = val;
    #pragma unroll
    for (int o = 32; o; o >>= 1) mx = fmaxf(mx, __shfl_xor(mx, o));
    float e = lane < 49 ? __expf(val - mx) : 0.f;
    float sm = e;
    #pragma unroll
    for (int o = 32; o; o >>= 1) sm += __shfl_xor(sm, o);
    if (lane < 49) S[r][lane] = e / sm;
  }
  __syncthreads();
  for (int idx = threadIdx.x; idx < 49 * 32; idx += 256) {
    int qr = idx >> 5, d = idx & 31;
    float acc = 0.f;
    #pragma unroll
    for (int kc = 0; kc < 49; ++kc)
      acc += S[qr][kc] * bf2f(vs[kc * 32 + d]);
    aout[(size_t)(win * 49 + qr) * C_ + head * 32 + d] = f2bf(acc);
  }
}

// ---- proj GEMM + reverse window/roll scatter + residual: writes x2 into d_out ----
__global__ __launch_bounds__(256) void k_proj(const ushort_t* __restrict__ ain,
                                              const ushort_t* __restrict__ wp,
                                              const float* __restrict__ pb,
                                              const float* __restrict__ x0,
                                              float* __restrict__ x2) {
  int wave = threadIdx.x >> 6, lane = threadIdx.x & 63;
  int lr = lane & 15, lk = (lane >> 4) * 8;
  int mbase = blockIdx.x * 128 + wave * 32;
  int nbase = blockIdx.y * 64;
  bf16v8 a[2][6];
  #pragma unroll
  for (int rt = 0; rt < 2; ++rt)
    #pragma unroll
    for (int kk = 0; kk < 6; ++kk)
      a[rt][kk] = ld8(ain + (size_t)(mbase + rt * 16 + lr) * C_ + kk * 32 + lk);
  for (int nt = 0; nt < 4; ++nt) {
    int ncol = nbase + nt * 16 + lr;
    f32x4 acc0 = {0.f, 0.f, 0.f, 0.f}, acc1 = {0.f, 0.f, 0.f, 0.f};
    #pragma unroll
    for (int kk = 0; kk < 6; ++kk) {
      bf16v8 bb = ld8(wp + (size_t)ncol * C_ + kk * 32 + lk);
      acc0 = __builtin_amdgcn_mfma_f32_16x16x32_bf16(a[0][kk], bb, acc0, 0, 0, 0);
      acc1 = __builtin_amdgcn_mfma_f32_16x16x32_bf16(a[1][kk], bb, acc1, 0, 0, 0);
    }
    float bias = pb[ncol];
    #pragma unroll
    for (int rt = 0; rt < 2; ++rt) {
      f32x4 acc = rt ? acc1 : acc0;
      #pragma unroll
      for (int i = 0; i < 4; ++i) {
        int gg = mbase + rt * 16 + (lane >> 4) * 4 + i;
        int win = gg / 49, tok = gg - win * 49;
        int bb2 = win >> 6, nw = win & 63;
        int wr = nw >> 3, wc = nw & 7;
        int ii = tok / 7, jj = tok - ii * 7;
        int hh = wr * 7 + ii + SHIFT_; if (hh >= HW_) hh -= HW_;
        int ww = wc * 7 + jj + SHIFT_; if (ww >= HW_) ww -= HW_;
        size_t dst = ((size_t)bb2 * 3136 + hh * 56 + ww) * C_ + ncol;
        x2[dst] = x0[dst] + acc[i] + bias;
      }
    }
  }
}

// ---- LN2: x2 (d_out) -> y2 bf16 ----
__global__ __launch_bounds__(256) void k_ln2(const float* __restrict__ x2,
                                             const float* __restrict__ g,
                                             const float* __restrict__ b,
                                             ushort_t* __restrict__ y2) {
  int wave = threadIdx.x >> 6, lane = threadIdx.x & 63;
  int gtok = blockIdx.x * 4 + wave;
  const float* row = x2 + (size_t)gtok * C_;
  float vals[3]; float s = 0.f, s2 = 0.f;
  #pragma unroll
  for (int r = 0; r < 3; ++r) { float t = row[lane + 64 * r]; vals[r] = t; s += t; s2 += t * t; }
  #pragma unroll
  for (int o = 32; o; o >>= 1) { s += __shfl_xor(s, o); s2 += __shfl_xor(s2, o); }
  float mean = s * (1.f / 192.f);
  float var  = s2 * (1.f / 192.f) - mean * mean;
  float rstd = rsqrtf(var + 1e-5f);
  ushort_t* orow = y2 + (size_t)gtok * C_;
  #pragma unroll
  for (int r = 0; r < 3; ++r) {
    int c = lane + 64 * r;
    orow[c] = f2bf((vals[r] - mean) * rstd * g[c] + b[c]);
  }
}

// ---- fused MLP: 128 rows/block, 4 waves x 32 rows, hidden chunked by 64,
//      fc1 -> GELU -> per-wave LDS round-trip -> fc2, no __syncthreads ----
__global__ __launch_bounds__(256, 2) void k_mlp(const ushort_t* __restrict__ y2,
                                                const ushort_t* __restrict__ w1,
                                                const float* __restrict__ b1,
                                                const ushort_t* __restrict__ w2,
                                                const float* __restrict__ b2,
                                                float* __restrict__ out) {
  // per-wave chunk buffer: 32 rows x 64 cols, row stride 72 ushorts = 144 B
  // (multiple of 16 B for ds_read_b128; stride mod 32 banks = 4 -> even spread)
  __shared__ ushort_t hbuf[4][32][72];
  int wave = threadIdx.x >> 6, lane = threadIdx.x & 63;
  int lr = lane & 15, lg = lane >> 4, lk = lg * 8;
  int mrow = blockIdx.x * 128 + wave * 32;

  // A1 fragments: 32 rows x 192 (held for whole kernel)
  bf16v8 a1[2][6];
  #pragma unroll
  for (int rt = 0; rt < 2; ++rt)
    #pragma unroll
    for (int kk = 0; kk < 6; ++kk)
      a1[rt][kk] = ld8(y2 + (size_t)(mrow + rt * 16 + lr) * C_ + kk * 32 + lk);

  f32x4 acc2[2][12];
  #pragma unroll
  for (int rt = 0; rt < 2; ++rt)
    #pragma unroll
    for (int nc = 0; nc < 12; ++nc)
      acc2[rt][nc] = (f32x4){0.f, 0.f, 0.f, 0.f};

  #pragma unroll 1
  for (int ch = 0; ch < 12; ++ch) {
    // ---- fc1: h_chunk(32x64) = A1 @ w1_chunk^T ----
    const ushort_t* w1c = w1 + (size_t)ch * 64 * C_;
    f32x4 acc1[2][4];
    #pragma unroll
    for (int rt = 0; rt < 2; ++rt)
      #pragma unroll
      for (int nt = 0; nt < 4; ++nt)
        acc1[rt][nt] = (f32x4){0.f, 0.f, 0.f, 0.f};
    #pragma unroll
    for (int nt = 0; nt < 4; ++nt) {
      #pragma unroll
      for (int kk = 0; kk < 6; ++kk) {
        bf16v8 bb = ld8(w1c + (size_t)(nt * 16 + lr) * C_ + kk * 32 + lk);
        acc1[0][nt] = __builtin_amdgcn_mfma_f32_16x16x32_bf16(a1[0][kk], bb, acc1[0][nt], 0, 0, 0);
        acc1[1][nt] = __builtin_amdgcn_mfma_f32_16x16x32_bf16(a1[1][kk], bb, acc1[1][nt], 0, 0, 0);
      }
    }
    // ---- bias + GELU -> per-wave LDS chunk ----
    float bs[4];
    #pragma unroll
    for (int nt = 0; nt < 4; ++nt) bs[nt] = b1[ch * 64 + nt * 16 + lr];
    #pragma unroll
    for (int rt = 0; rt < 2; ++rt)
      #pragma unroll
      for (int nt = 0; nt < 4; ++nt)
        #pragma unroll
        for (int i = 0; i < 4; ++i) {
          int row = rt * 16 + lg * 4 + i;
          hbuf[wave][row][nt * 16 + lr] = f2bf(gelu_f(acc1[rt][nt][i] + bs[nt]));
        }
    asm volatile("s_waitcnt lgkmcnt(0)" ::: "memory");
    // ---- read back as A-fragments (k = chunk cols) ----
    bf16v8 a2[2][2];
    #pragma unroll
    for (int rt = 0; rt < 2; ++rt)
      #pragma unroll
      for (int kk = 0; kk < 2; ++kk)
        a2[rt][kk] = ld8(&hbuf[wave][rt * 16 + lr][kk * 32 + lk]);
    // ---- fc2 partial: acc2 += h_chunk @ w2_chunk^T ----
    #pragma unroll
    for (int nc = 0; nc < 12; ++nc) {
      int ncol = nc * 16 + lr;
      #pragma unroll
      for (int kk = 0; kk < 2; ++kk) {
        bf16v8 bb = ld8(w2 + (size_t)ncol * HID_ + ch * 64 + kk * 32 + lk);
        acc2[0][nc] = __builtin_amdgcn_mfma_f32_16x16x32_bf16(a2[0][kk], bb, acc2[0][nc], 0, 0, 0);
        acc2[1][nc] = __builtin_amdgcn_mfma_f32_16x16x32_bf16(a2[1][kk], bb, acc2[1][nc], 0, 0, 0);
      }
    }
  }
  // ---- epilogue: bias + residual RMW on out (holds x2) ----
  #pragma unroll
  for (int nc = 0; nc < 12; ++nc) {
    float bias = b2[nc * 16 + lr];
    #pragma unroll
    for (int rt = 0; rt < 2; ++rt)
      #pragma unroll
      for (int i = 0; i < 4; ++i) {
        size_t o = (size_t)(mrow + rt * 16 + lg * 4 + i) * C_ + nc * 16 + lr;
        out[o] = out[o] + acc2[rt][nc][i] + bias;
      }
  }
}

extern "C" void kernel_launch(void* const* d_in, const int* in_sizes, int n_in,
                              void* d_out, int out_size, void* d_ws, size_t ws_size,
                              hipStream_t stream) {
  const float* x     = (const float*)d_in[0];
  const float* n1g   = (const float*)d_in[1];
  const float* n1b   = (const float*)d_in[2];
  const float* qkvw  = (const float*)d_in[3];
  const float* qkvb  = (const float*)d_in[4];
  const float* rpb   = (const float*)d_in[5];
  const float* projw = (const float*)d_in[6];
  const float* projb = (const float*)d_in[7];
  const float* n2g   = (const float*)d_in[8];
  const float* n2b   = (const float*)d_in[9];
  const float* fc1w  = (const float*)d_in[10];
  const float* fc1b  = (const float*)d_in[11];
  const float* fc2w  = (const float*)d_in[12];
  const float* fc2b  = (const float*)d_in[13];
  const int*   relidx= (const int*)d_in[14];
  const float* amask = (const float*)d_in[15];
  float* out = (float*)d_out;

  const size_t MC = (size_t)M_ * C_;
  ushort_t* ws = (ushort_t*)d_ws;
  ushort_t* xw = ws;                 // (M,192) bf16; later reused as attn_out
  ushort_t* q  = ws + MC;            // (nwin,heads,tok,hd); later reused as y2
  ushort_t* k  = ws + 2 * MC;
  ushort_t* v  = ws + 3 * MC;
  ushort_t* wq = ws + 4 * MC;
  ushort_t* wp = wq + (size_t)C3_ * C_;
  ushort_t* w1 = wp + (size_t)C_ * C_;
  ushort_t* w2 = w1 + (size_t)HID_ * C_;

  int n0 = C3_ * C_, n1 = C_ * C_, n2 = HID_ * C_, n3 = C_ * HID_;
  k_f2b4<<<(n0 + n1 + n2 + n3 + 255) / 256, 256, 0, stream>>>(
      qkvw, wq, n0, projw, wp, n1, fc1w, w1, n2, fc2w, w2, n3);

  k_ln1<<<M_ / 4, 256, 0, stream>>>(x, n1g, n1b, xw);
  k_qkv<<<dim3(M_ / 128, C3_ / 64), 256, 0, stream>>>(xw, wq, qkvb, q, k, v);
  k_attn<<<NWIN_ * HEADS_, 256, 0, stream>>>(q, k, v, rpb, relidx, amask, xw);
  k_proj<<<dim3(M_ / 128, C_ / 64), 256, 0, stream>>>(xw, wp, projb, x, out);
  k_ln2<<<M_ / 4, 256, 0, stream>>>(out, n2g, n2b, q);
  k_mlp<<<M_ / 128, 256, 0, stream>>>(q, w1, fc1b, w2, fc2b, out);
}

// Round 3
// 1343.329 us; speedup vs baseline: 1.3498x; 1.3498x over previous
//
#include <hip/hip_runtime.h>
#include <hip/hip_bf16.h>

// ---- problem constants ----
#define B_      64
#define HW_     56        // H == W == 56
#define C_      192
#define HEADS_  6
#define HD_     32
#define WS_     7
#define TOK_    49
#define NW_     64        // windows per image (8x8)
#define NWIN_   4096      // B_*NW_
#define M_      200704    // NWIN_*TOK_
#define C3_     576
#define HID_    768
#define SHIFT_  3

typedef unsigned short ushort_t;
typedef __bf16 bf16v8 __attribute__((ext_vector_type(8)));
typedef float  f32x4  __attribute__((ext_vector_type(4)));

__device__ inline float bf2f(ushort_t u) {
  union { unsigned int i; float f; } c; c.i = ((unsigned int)u) << 16; return c.f;
}
__device__ inline ushort_t f2bf(float f) {
  union { float f; unsigned int u; } c; c.f = f;
  unsigned int u = c.u;
  return (ushort_t)((u + 0x7fffu + ((u >> 16) & 1u)) >> 16);  // RNE
}
__device__ inline bf16v8 ld8(const ushort_t* p) { return *(const bf16v8*)p; }
__device__ inline void st8(ushort_t* p, bf16v8 v) { *(bf16v8*)p = v; }

// exact-GELU via Abramowitz-Stegun 7.1.26 erf (max err 1.5e-7)
__device__ inline float gelu_f(float x) {
  float z = fabsf(x) * 0.70710678118654752f;
  float t = __builtin_amdgcn_rcpf(fmaf(0.3275911f, z, 1.0f));
  float p = fmaf(fmaf(fmaf(fmaf(1.061405429f, t, -1.453152027f), t,
                           1.421413741f), t, -0.284496736f), t, 0.254829592f);
  p *= t;
  float e = __expf(-z * z);
  float erfa = fmaf(-p, e, 1.0f);
  unsigned s = __float_as_uint(x) & 0x80000000u;
  float erfs = __uint_as_float(__float_as_uint(erfa) | s);
  return 0.5f * x * (1.0f + erfs);
}

// ---- fp32 -> bf16 weight convert (all 4 weights, one launch) ----
__global__ __launch_bounds__(256) void k_f2b4(const float* __restrict__ s0, ushort_t* __restrict__ d0, int n0,
                                              const float* __restrict__ s1, ushort_t* __restrict__ d1, int n1,
                                              const float* __restrict__ s2, ushort_t* __restrict__ d2, int n2,
                                              const float* __restrict__ s3, ushort_t* __restrict__ d3, int n3) {
  int i = blockIdx.x * 256 + threadIdx.x;
  if (i < n0) { d0[i] = f2bf(s0[i]); return; }
  i -= n0;
  if (i < n1) { d1[i] = f2bf(s1[i]); return; }
  i -= n1;
  if (i < n2) { d2[i] = f2bf(s2[i]); return; }
  i -= n2;
  if (i < n3) { d3[i] = f2bf(s3[i]); }
}

// ---- LN1 + roll(-3,-3) + window partition gather: x (B,H,W,C) -> xw bf16 (M,192) ----
__global__ __launch_bounds__(256) void k_ln1(const float* __restrict__ x,
                                             const float* __restrict__ g,
                                             const float* __restrict__ b,
                                             ushort_t* __restrict__ xw) {
  int wave = threadIdx.x >> 6, lane = threadIdx.x & 63;
  int gtok = blockIdx.x * 4 + wave;           // window-order token index
  int win = gtok / 49, tok = gtok - win * 49;
  int bb = win >> 6, nw = win & 63;
  int wr = nw >> 3, wc = nw & 7;
  int ii = tok / 7, jj = tok - ii * 7;
  int hh = wr * 7 + ii + SHIFT_; if (hh >= HW_) hh -= HW_;
  int ww = wc * 7 + jj + SHIFT_; if (ww >= HW_) ww -= HW_;
  const float* row = x + ((size_t)bb * 3136 + hh * 56 + ww) * C_;
  float vals[3]; float s = 0.f, s2 = 0.f;
  #pragma unroll
  for (int r = 0; r < 3; ++r) { float t = row[lane + 64 * r]; vals[r] = t; s += t; s2 += t * t; }
  #pragma unroll
  for (int o = 32; o; o >>= 1) { s += __shfl_xor(s, o); s2 += __shfl_xor(s2, o); }
  float mean = s * (1.f / 192.f);
  float var  = s2 * (1.f / 192.f) - mean * mean;
  float rstd = rsqrtf(var + 1e-5f);
  ushort_t* orow = xw + (size_t)gtok * C_;
  #pragma unroll
  for (int r = 0; r < 3; ++r) {
    int c = lane + 64 * r;
    orow[c] = f2bf((vals[r] - mean) * rstd * g[c] + b[c]);
  }
}

// ---- QKV GEMM (staged-B, double-buffered, 1 barrier/tile):
//      xw (M,192) @ wq^T (576,192) + bias -> q,k,v (nwin,heads,tok,hd) bf16 ----
__global__ __launch_bounds__(512, 4) void k_qkv(const ushort_t* __restrict__ xw,
                                                const ushort_t* __restrict__ wq,
                                                const float* __restrict__ qkvb,
                                                ushort_t* __restrict__ q,
                                                ushort_t* __restrict__ k,
                                                ushort_t* __restrict__ v) {
  __shared__ ushort_t bbuf[2][64][200];   // row stride 400B: 16B-aligned, 4 mod 32 banks
  int tid = threadIdx.x, wave = tid >> 6, lane = tid & 63;
  int lr = lane & 15, lg = lane >> 4, lk = lg * 8;
  int mbase = blockIdx.x * 256 + wave * 32;
  // A fragments: wave's 32 rows x 192
  bf16v8 a[2][6];
  #pragma unroll
  for (int rt = 0; rt < 2; ++rt)
    #pragma unroll
    for (int kk = 0; kk < 6; ++kk)
      a[rt][kk] = ld8(xw + (size_t)(mbase + rt * 16 + lr) * C_ + kk * 32 + lk);
  // prologue: stage tile 0
  int se[3], sr[3], sc[3];
  #pragma unroll
  for (int t = 0; t < 3; ++t) {
    se[t] = (tid + t * 512) * 8; sr[t] = se[t] / 192; sc[t] = se[t] - sr[t] * 192;
  }
  {
    bf16v8 st[3];
    #pragma unroll
    for (int t = 0; t < 3; ++t) st[t] = ld8(wq + (size_t)sr[t] * C_ + sc[t]);
    #pragma unroll
    for (int t = 0; t < 3; ++t) st8(&bbuf[0][sr[t]][sc[t]], st[t]);
  }
  __syncthreads();
  int cur = 0;
  for (int nt = 0; nt < 9; ++nt) {
    int nbase = nt * 64;
    bf16v8 st[3];
    if (nt < 8) {
      #pragma unroll
      for (int t = 0; t < 3; ++t)
        st[t] = ld8(wq + (size_t)(nbase + 64 + sr[t]) * C_ + sc[t]);
    }
    f32x4 acc[2][4];
    #pragma unroll
    for (int rt = 0; rt < 2; ++rt)
      #pragma unroll
      for (int s = 0; s < 4; ++s) acc[rt][s] = (f32x4){0.f, 0.f, 0.f, 0.f};
    #pragma unroll
    for (int s = 0; s < 4; ++s)
      #pragma unroll
      for (int kk = 0; kk < 6; ++kk) {
        bf16v8 bb = ld8(&bbuf[cur][s * 16 + lr][kk * 32 + lk]);
        acc[0][s] = __builtin_amdgcn_mfma_f32_16x16x32_bf16(a[0][kk], bb, acc[0][s], 0, 0, 0);
        acc[1][s] = __builtin_amdgcn_mfma_f32_16x16x32_bf16(a[1][kk], bb, acc[1][s], 0, 0, 0);
      }
    // epilogue scatter
    #pragma unroll
    for (int s = 0; s < 4; ++s) {
      int ncol = nbase + s * 16 + lr;
      float bias = qkvb[ncol];
      int sec = ncol / 192, cm = ncol - sec * 192;
      int head = cm >> 5, dd = cm & 31;
      ushort_t* dst = sec == 0 ? q : (sec == 1 ? k : v);
      #pragma unroll
      for (int rt = 0; rt < 2; ++rt)
        #pragma unroll
        for (int i = 0; i < 4; ++i) {
          int gg = mbase + rt * 16 + lg * 4 + i;
          int win = gg / 49, tok = gg - win * 49;
          dst[((size_t)(win * 6 + head) * 49 + tok) * 32 + dd] = f2bf(acc[rt][s][i] + bias);
        }
    }
    if (nt < 8) {
      #pragma unroll
      for (int t = 0; t < 3; ++t) st8(&bbuf[cur ^ 1][sr[t]][sc[t]], st[t]);
    }
    __syncthreads();
    cur ^= 1;
  }
}

// ---- attention per (window, head) ----
__global__ __launch_bounds__(256) void k_attn(const ushort_t* __restrict__ q,
                                              const ushort_t* __restrict__ k,
                                              const ushort_t* __restrict__ v,
                                              const float* __restrict__ rpb,
                                              const int* __restrict__ relidx,
                                              const float* __restrict__ amask,
                                              ushort_t* __restrict__ aout) {
  __shared__ ushort_t qs[49 * 32];
  __shared__ ushort_t kst[32 * 52];   // transposed [d][kc], padded
  __shared__ ushort_t vs[49 * 32];
  __shared__ float S[49][52];
  int wh = blockIdx.x;
  int win = wh / 6, head = wh - win * 6;
  int nw = win & 63;
  const size_t base = (size_t)wh * (49 * 32);
  for (int idx = threadIdx.x; idx < 49 * 32; idx += 256) {
    int kc = idx >> 5, d = idx & 31;
    qs[idx] = q[base + idx];
    kst[d * 52 + kc] = k[base + idx];
    vs[idx] = v[base + idx];
  }
  __syncthreads();
  const float scale = 0.17677669529663687f;  // 1/sqrt(32)
  for (int p = threadIdx.x; p < 49 * 49; p += 256) {
    int qr = p / 49, kc = p - qr * 49;
    float acc = 0.f;
    #pragma unroll
    for (int d = 0; d < 32; ++d)
      acc += bf2f(qs[qr * 32 + d]) * bf2f(kst[d * 52 + kc]);
    float bias = rpb[relidx[p] * 6 + head];
    float mval = amask[(size_t)nw * (49 * 49) + p];
    S[qr][kc] = acc * scale + bias + mval;
  }
  __syncthreads();
  int wave = threadIdx.x >> 6, lane = threadIdx.x & 63;
  for (int r = wave; r < 49; r += 4) {
    float val = lane < 49 ? S[r][lane] : -1e30f;
    float mx = val;
    #pragma unroll
    for (int o = 32; o; o >>= 1) mx = fmaxf(mx, __shfl_xor(mx, o));
    float e = lane < 49 ? __expf(val - mx) : 0.f;
    float sm = e;
    #pragma unroll
    for (int o = 32; o; o >>= 1) sm += __shfl_xor(sm, o);
    if (lane < 49) S[r][lane] = e / sm;
  }
  __syncthreads();
  for (int idx = threadIdx.x; idx < 49 * 32; idx += 256) {
    int qr = idx >> 5, d = idx & 31;
    float acc = 0.f;
    #pragma unroll
    for (int kc = 0; kc < 49; ++kc)
      acc += S[qr][kc] * bf2f(vs[kc * 32 + d]);
    aout[(size_t)(win * 49 + qr) * C_ + head * 32 + d] = f2bf(acc);
  }
}

// ---- proj GEMM (staged-B) + reverse window/roll scatter + residual -> d_out ----
__global__ __launch_bounds__(512, 4) void k_proj(const ushort_t* __restrict__ ain,
                                                 const ushort_t* __restrict__ wp,
                                                 const float* __restrict__ pb,
                                                 const float* __restrict__ x0,
                                                 float* __restrict__ x2) {
  __shared__ ushort_t bbuf[2][64][200];
  int tid = threadIdx.x, wave = tid >> 6, lane = tid & 63;
  int lr = lane & 15, lg = lane >> 4, lk = lg * 8;
  int mbase = blockIdx.x * 256 + wave * 32;
  bf16v8 a[2][6];
  #pragma unroll
  for (int rt = 0; rt < 2; ++rt)
    #pragma unroll
    for (int kk = 0; kk < 6; ++kk)
      a[rt][kk] = ld8(ain + (size_t)(mbase + rt * 16 + lr) * C_ + kk * 32 + lk);
  int se[3], sr[3], sc[3];
  #pragma unroll
  for (int t = 0; t < 3; ++t) {
    se[t] = (tid + t * 512) * 8; sr[t] = se[t] / 192; sc[t] = se[t] - sr[t] * 192;
  }
  {
    bf16v8 st[3];
    #pragma unroll
    for (int t = 0; t < 3; ++t) st[t] = ld8(wp + (size_t)sr[t] * C_ + sc[t]);
    #pragma unroll
    for (int t = 0; t < 3; ++t) st8(&bbuf[0][sr[t]][sc[t]], st[t]);
  }
  __syncthreads();
  int cur = 0;
  for (int nt = 0; nt < 3; ++nt) {
    int nbase = nt * 64;
    bf16v8 st[3];
    if (nt < 2) {
      #pragma unroll
      for (int t = 0; t < 3; ++t)
        st[t] = ld8(wp + (size_t)(nbase + 64 + sr[t]) * C_ + sc[t]);
    }
    f32x4 acc[2][4];
    #pragma unroll
    for (int rt = 0; rt < 2; ++rt)
      #pragma unroll
      for (int s = 0; s < 4; ++s) acc[rt][s] = (f32x4){0.f, 0.f, 0.f, 0.f};
    #pragma unroll
    for (int s = 0; s < 4; ++s)
      #pragma unroll
      for (int kk = 0; kk < 6; ++kk) {
        bf16v8 bb = ld8(&bbuf[cur][s * 16 + lr][kk * 32 + lk]);
        acc[0][s] = __builtin_amdgcn_mfma_f32_16x16x32_bf16(a[0][kk], bb, acc[0][s], 0, 0, 0);
        acc[1][s] = __builtin_amdgcn_mfma_f32_16x16x32_bf16(a[1][kk], bb, acc[1][s], 0, 0, 0);
      }
    #pragma unroll
    for (int s = 0; s < 4; ++s) {
      int ncol = nbase + s * 16 + lr;
      float bias = pb[ncol];
      #pragma unroll
      for (int rt = 0; rt < 2; ++rt)
        #pragma unroll
        for (int i = 0; i < 4; ++i) {
          int gg = mbase + rt * 16 + lg * 4 + i;
          int win = gg / 49, tok = gg - win * 49;
          int bb2 = win >> 6, nw = win & 63;
          int wr = nw >> 3, wc = nw & 7;
          int ii = tok / 7, jj = tok - ii * 7;
          int hh = wr * 7 + ii + SHIFT_; if (hh >= HW_) hh -= HW_;
          int ww = wc * 7 + jj + SHIFT_; if (ww >= HW_) ww -= HW_;
          size_t dst = ((size_t)bb2 * 3136 + hh * 56 + ww) * C_ + ncol;
          x2[dst] = x0[dst] + acc[rt][s][i] + bias;
        }
    }
    if (nt < 2) {
      #pragma unroll
      for (int t = 0; t < 3; ++t) st8(&bbuf[cur ^ 1][sr[t]][sc[t]], st[t]);
    }
    __syncthreads();
    cur ^= 1;
  }
}

// ---- LN2: x2 (d_out) -> y2 bf16 ----
__global__ __launch_bounds__(256) void k_ln2(const float* __restrict__ x2,
                                             const float* __restrict__ g,
                                             const float* __restrict__ b,
                                             ushort_t* __restrict__ y2) {
  int wave = threadIdx.x >> 6, lane = threadIdx.x & 63;
  int gtok = blockIdx.x * 4 + wave;
  const float* row = x2 + (size_t)gtok * C_;
  float vals[3]; float s = 0.f, s2 = 0.f;
  #pragma unroll
  for (int r = 0; r < 3; ++r) { float t = row[lane + 64 * r]; vals[r] = t; s += t; s2 += t * t; }
  #pragma unroll
  for (int o = 32; o; o >>= 1) { s += __shfl_xor(s, o); s2 += __shfl_xor(s2, o); }
  float mean = s * (1.f / 192.f);
  float var  = s2 * (1.f / 192.f) - mean * mean;
  float rstd = rsqrtf(var + 1e-5f);
  ushort_t* orow = y2 + (size_t)gtok * C_;
  #pragma unroll
  for (int r = 0; r < 3; ++r) {
    int c = lane + 64 * r;
    orow[c] = f2bf((vals[r] - mean) * rstd * g[c] + b[c]);
  }
}

// ---- fused MLP (staged weights, dbuf, 1 barrier/chunk):
//      fc1 -> GELU -> per-wave LDS half-bounce -> fc2 -> residual RMW ----
__global__ __launch_bounds__(512, 2) void k_mlp(const ushort_t* __restrict__ y2,
                                                const ushort_t* __restrict__ w1,
                                                const float* __restrict__ b1,
                                                const ushort_t* __restrict__ w2,
                                                const float* __restrict__ b2,
                                                float* __restrict__ out) {
  __shared__ ushort_t w1buf[2][64][200];    // 51.2 KB: chunk rows of w1
  __shared__ ushort_t w2buf[2][192][72];    // 55.3 KB: all 192 out-cols x 64 chunk-k
  __shared__ ushort_t hbuf[8][32][40];      // 20.5 KB: per-wave GELU bounce (32-col half)
  int tid = threadIdx.x, wave = tid >> 6, lane = tid & 63;
  int lr = lane & 15, lg = lane >> 4, lk = lg * 8;
  int mrow = blockIdx.x * 256 + wave * 32;

  // stage index precompute: w1 chunk (64x192), w2 chunk (192x64)
  int e1[3], r1[3], c1[3], e2[3], r2[3], c2[3];
  #pragma unroll
  for (int t = 0; t < 3; ++t) {
    e1[t] = (tid + t * 512) * 8; r1[t] = e1[t] / 192; c1[t] = e1[t] - r1[t] * 192;
    e2[t] = (tid + t * 512) * 8; r2[t] = e2[t] / 64;  c2[t] = e2[t] - r2[t] * 64;
  }

  // A1 fragments: 32 rows x 192 (held for whole kernel)
  bf16v8 a1[2][6];
  #pragma unroll
  for (int rt = 0; rt < 2; ++rt)
    #pragma unroll
    for (int kk = 0; kk < 6; ++kk)
      a1[rt][kk] = ld8(y2 + (size_t)(mrow + rt * 16 + lr) * C_ + kk * 32 + lk);

  f32x4 acc2[2][12];
  #pragma unroll
  for (int rt = 0; rt < 2; ++rt)
    #pragma unroll
    for (int nc = 0; nc < 12; ++nc)
      acc2[rt][nc] = (f32x4){0.f, 0.f, 0.f, 0.f};

  // prologue: stage chunk 0
  {
    bf16v8 s1v[3], s2v[3];
    #pragma unroll
    for (int t = 0; t < 3; ++t) {
      s1v[t] = ld8(w1 + (size_t)r1[t] * C_ + c1[t]);
      s2v[t] = ld8(w2 + (size_t)r2[t] * HID_ + c2[t]);
    }
    #pragma unroll
    for (int t = 0; t < 3; ++t) {
      st8(&w1buf[0][r1[t]][c1[t]], s1v[t]);
      st8(&w2buf[0][r2[t]][c2[t]], s2v[t]);
    }
  }
  __syncthreads();
  int cur = 0;

  #pragma unroll 1
  for (int ch = 0; ch < 12; ++ch) {
    // issue next chunk's staging loads early (latency hides under compute)
    bf16v8 s1v[3], s2v[3];
    if (ch < 11) {
      #pragma unroll
      for (int t = 0; t < 3; ++t) {
        s1v[t] = ld8(w1 + (size_t)((ch + 1) * 64 + r1[t]) * C_ + c1[t]);
        s2v[t] = ld8(w2 + (size_t)r2[t] * HID_ + (ch + 1) * 64 + c2[t]);
      }
    }
    // ---- fc1: h_chunk(32x64) = A1 @ w1c^T ----
    f32x4 acc1[2][4];
    #pragma unroll
    for (int rt = 0; rt < 2; ++rt)
      #pragma unroll
      for (int nt = 0; nt < 4; ++nt) acc1[rt][nt] = (f32x4){0.f, 0.f, 0.f, 0.f};
    #pragma unroll
    for (int nt = 0; nt < 4; ++nt)
      #pragma unroll
      for (int kk = 0; kk < 6; ++kk) {
        bf16v8 bb = ld8(&w1buf[cur][nt * 16 + lr][kk * 32 + lk]);
        acc1[0][nt] = __builtin_amdgcn_mfma_f32_16x16x32_bf16(a1[0][kk], bb, acc1[0][nt], 0, 0, 0);
        acc1[1][nt] = __builtin_amdgcn_mfma_f32_16x16x32_bf16(a1[1][kk], bb, acc1[1][nt], 0, 0, 0);
      }
    float bs[4];
    #pragma unroll
    for (int nt = 0; nt < 4; ++nt) bs[nt] = b1[ch * 64 + nt * 16 + lr];
    // ---- two 32-col halves: GELU -> hbuf -> a2 -> fc2 partial ----
    #pragma unroll
    for (int hf = 0; hf < 2; ++hf) {
      #pragma unroll
      for (int rt = 0; rt < 2; ++rt)
        #pragma unroll
        for (int nt2 = 0; nt2 < 2; ++nt2) {
          int nt = hf * 2 + nt2;
          #pragma unroll
          for (int i = 0; i < 4; ++i) {
            int row = rt * 16 + lg * 4 + i;
            hbuf[wave][row][nt2 * 16 + lr] = f2bf(gelu_f(acc1[rt][nt][i] + bs[nt]));
          }
        }
      bf16v8 a2[2];
      #pragma unroll
      for (int rt = 0; rt < 2; ++rt)
        a2[rt] = ld8(&hbuf[wave][rt * 16 + lr][lk]);
      #pragma unroll
      for (int nc = 0; nc < 12; ++nc) {
        bf16v8 bb = ld8(&w2buf[cur][nc * 16 + lr][hf * 32 + lk]);
        acc2[0][nc] = __builtin_amdgcn_mfma_f32_16x16x32_bf16(a2[0], bb, acc2[0][nc], 0, 0, 0);
        acc2[1][nc] = __builtin_amdgcn_mfma_f32_16x16x32_bf16(a2[1], bb, acc2[1][nc], 0, 0, 0);
      }
    }
    // ---- write next chunk's stage, one barrier ----
    if (ch < 11) {
      #pragma unroll
      for (int t = 0; t < 3; ++t) {
        st8(&w1buf[cur ^ 1][r1[t]][c1[t]], s1v[t]);
        st8(&w2buf[cur ^ 1][r2[t]][c2[t]], s2v[t]);
      }
    }
    __syncthreads();
    cur ^= 1;
  }
  // ---- epilogue: bias + residual RMW on out (holds x2) ----
  #pragma unroll
  for (int nc = 0; nc < 12; ++nc) {
    float bias = b2[nc * 16 + lr];
    #pragma unroll
    for (int rt = 0; rt < 2; ++rt)
      #pragma unroll
      for (int i = 0; i < 4; ++i) {
        size_t o = (size_t)(mrow + rt * 16 + lg * 4 + i) * C_ + nc * 16 + lr;
        out[o] = out[o] + acc2[rt][nc][i] + bias;
      }
  }
}

extern "C" void kernel_launch(void* const* d_in, const int* in_sizes, int n_in,
                              void* d_out, int out_size, void* d_ws, size_t ws_size,
                              hipStream_t stream) {
  const float* x     = (const float*)d_in[0];
  const float* n1g   = (const float*)d_in[1];
  const float* n1b   = (const float*)d_in[2];
  const float* qkvw  = (const float*)d_in[3];
  const float* qkvb  = (const float*)d_in[4];
  const float* rpb   = (const float*)d_in[5];
  const float* projw = (const float*)d_in[6];
  const float* projb = (const float*)d_in[7];
  const float* n2g   = (const float*)d_in[8];
  const float* n2b   = (const float*)d_in[9];
  const float* fc1w  = (const float*)d_in[10];
  const float* fc1b  = (const float*)d_in[11];
  const float* fc2w  = (const float*)d_in[12];
  const float* fc2b  = (const float*)d_in[13];
  const int*   relidx= (const int*)d_in[14];
  const float* amask = (const float*)d_in[15];
  float* out = (float*)d_out;

  const size_t MC = (size_t)M_ * C_;
  ushort_t* ws = (ushort_t*)d_ws;
  ushort_t* xw = ws;                 // (M,192) bf16; later reused as attn_out
  ushort_t* q  = ws + MC;            // (nwin,heads,tok,hd); later reused as y2
  ushort_t* k  = ws + 2 * MC;
  ushort_t* v  = ws + 3 * MC;
  ushort_t* wq = ws + 4 * MC;
  ushort_t* wp = wq + (size_t)C3_ * C_;
  ushort_t* w1 = wp + (size_t)C_ * C_;
  ushort_t* w2 = w1 + (size_t)HID_ * C_;

  int n0 = C3_ * C_, n1 = C_ * C_, n2 = HID_ * C_, n3 = C_ * HID_;
  k_f2b4<<<(n0 + n1 + n2 + n3 + 255) / 256, 256, 0, stream>>>(
      qkvw, wq, n0, projw, wp, n1, fc1w, w1, n2, fc2w, w2, n3);

  k_ln1<<<M_ / 4, 256, 0, stream>>>(x, n1g, n1b, xw);
  k_qkv<<<M_ / 256, 512, 0, stream>>>(xw, wq, qkvb, q, k, v);
  k_attn<<<NWIN_ * HEADS_, 256, 0, stream>>>(q, k, v, rpb, relidx, amask, xw);
  k_proj<<<M_ / 256, 512, 0, stream>>>(xw, wp, projb, x, out);
  k_ln2<<<M_ / 4, 256, 0, stream>>>(out, n2g, n2b, q);
  k_mlp<<<M_ / 256, 512, 0, stream>>>(q, w1, fc1b, w2, fc2b, out);
}

// Round 5
// 996.467 us; speedup vs baseline: 1.8197x; 1.3481x over previous
//
#include <hip/hip_runtime.h>
#include <hip/hip_bf16.h>

// ---- problem constants ----
#define B_      64
#define HW_     56        // H == W == 56
#define C_      192
#define HEADS_  6
#define HD_     32
#define WS_     7
#define TOK_    49
#define NW_     64        // windows per image (8x8)
#define NWIN_   4096      // B_*NW_
#define M_      200704    // NWIN_*TOK_
#define C3_     576
#define HID_    768
#define SHIFT_  3

typedef unsigned short ushort_t;
typedef __bf16 bf16v8 __attribute__((ext_vector_type(8)));
typedef unsigned short u16v8 __attribute__((ext_vector_type(8)));
typedef float  f32x4  __attribute__((ext_vector_type(4)));

__device__ inline float bf2f(ushort_t u) {
  union { unsigned int i; float f; } c; c.i = ((unsigned int)u) << 16; return c.f;
}
__device__ inline ushort_t f2bf(float f) {
  union { float f; unsigned int u; } c; c.f = f;
  unsigned int u = c.u;
  return (ushort_t)((u + 0x7fffu + ((u >> 16) & 1u)) >> 16);  // RNE
}
__device__ inline bf16v8 ld8(const ushort_t* p) { return *(const bf16v8*)p; }
__device__ inline void st8(ushort_t* p, bf16v8 v) { *(bf16v8*)p = v; }

// exact-GELU via Abramowitz-Stegun 7.1.26 erf (max err 1.5e-7)
__device__ inline float gelu_f(float x) {
  float z = fabsf(x) * 0.70710678118654752f;
  float t = __builtin_amdgcn_rcpf(fmaf(0.3275911f, z, 1.0f));
  float p = fmaf(fmaf(fmaf(fmaf(1.061405429f, t, -1.453152027f), t,
                           1.421413741f), t, -0.284496736f), t, 0.254829592f);
  p *= t;
  float e = __expf(-z * z);
  float erfa = fmaf(-p, e, 1.0f);
  unsigned s = __float_as_uint(x) & 0x80000000u;
  float erfs = __uint_as_float(__float_as_uint(erfa) | s);
  return 0.5f * x * (1.0f + erfs);
}

// ---- fp32 -> bf16 weight convert (all 4 weights, one launch) ----
__global__ __launch_bounds__(256) void k_f2b4(const float* __restrict__ s0, ushort_t* __restrict__ d0, int n0,
                                              const float* __restrict__ s1, ushort_t* __restrict__ d1, int n1,
                                              const float* __restrict__ s2, ushort_t* __restrict__ d2, int n2,
                                              const float* __restrict__ s3, ushort_t* __restrict__ d3, int n3) {
  int i = blockIdx.x * 256 + threadIdx.x;
  if (i < n0) { d0[i] = f2bf(s0[i]); return; }
  i -= n0;
  if (i < n1) { d1[i] = f2bf(s1[i]); return; }
  i -= n1;
  if (i < n2) { d2[i] = f2bf(s2[i]); return; }
  i -= n2;
  if (i < n3) { d3[i] = f2bf(s3[i]); }
}

// ---- LN1 + roll(-3,-3) + window partition gather: x (B,H,W,C) -> xw bf16 (M,192) ----
__global__ __launch_bounds__(256) void k_ln1(const float* __restrict__ x,
                                             const float* __restrict__ g,
                                             const float* __restrict__ b,
                                             ushort_t* __restrict__ xw) {
  int wave = threadIdx.x >> 6, lane = threadIdx.x & 63;
  int gtok = blockIdx.x * 4 + wave;           // window-order token index
  int win = gtok / 49, tok = gtok - win * 49;
  int bb = win >> 6, nw = win & 63;
  int wr = nw >> 3, wc = nw & 7;
  int ii = tok / 7, jj = tok - ii * 7;
  int hh = wr * 7 + ii + SHIFT_; if (hh >= HW_) hh -= HW_;
  int ww = wc * 7 + jj + SHIFT_; if (ww >= HW_) ww -= HW_;
  const float* row = x + ((size_t)bb * 3136 + hh * 56 + ww) * C_;
  float vals[3]; float s = 0.f, s2 = 0.f;
  #pragma unroll
  for (int r = 0; r < 3; ++r) { float t = row[lane + 64 * r]; vals[r] = t; s += t; s2 += t * t; }
  #pragma unroll
  for (int o = 32; o; o >>= 1) { s += __shfl_xor(s, o); s2 += __shfl_xor(s2, o); }
  float mean = s * (1.f / 192.f);
  float var  = s2 * (1.f / 192.f) - mean * mean;
  float rstd = rsqrtf(var + 1e-5f);
  ushort_t* orow = xw + (size_t)gtok * C_;
  #pragma unroll
  for (int r = 0; r < 3; ++r) {
    int c = lane + 64 * r;
    orow[c] = f2bf((vals[r] - mean) * rstd * g[c] + b[c]);
  }
}

// ---- QKV GEMM (staged-B, double-buffered, 1 barrier/tile):
//      xw (M,192) @ wq^T (576,192) + bias -> q,k,v (nwin,heads,tok,hd) bf16
//      NOTE: q is pre-scaled by 1/sqrt(hd) here. ----
__global__ __launch_bounds__(512, 4) void k_qkv(const ushort_t* __restrict__ xw,
                                                const ushort_t* __restrict__ wq,
                                                const float* __restrict__ qkvb,
                                                ushort_t* __restrict__ q,
                                                ushort_t* __restrict__ k,
                                                ushort_t* __restrict__ v) {
  __shared__ ushort_t bbuf[2][64][200];   // row stride 400B: 16B-aligned, 4 mod 32 banks
  int tid = threadIdx.x, wave = tid >> 6, lane = tid & 63;
  int lr = lane & 15, lg = lane >> 4, lk = lg * 8;
  int mbase = blockIdx.x * 256 + wave * 32;
  bf16v8 a[2][6];
  #pragma unroll
  for (int rt = 0; rt < 2; ++rt)
    #pragma unroll
    for (int kk = 0; kk < 6; ++kk)
      a[rt][kk] = ld8(xw + (size_t)(mbase + rt * 16 + lr) * C_ + kk * 32 + lk);
  int se[3], sr[3], sc[3];
  #pragma unroll
  for (int t = 0; t < 3; ++t) {
    se[t] = (tid + t * 512) * 8; sr[t] = se[t] / 192; sc[t] = se[t] - sr[t] * 192;
  }
  {
    bf16v8 st[3];
    #pragma unroll
    for (int t = 0; t < 3; ++t) st[t] = ld8(wq + (size_t)sr[t] * C_ + sc[t]);
    #pragma unroll
    for (int t = 0; t < 3; ++t) st8(&bbuf[0][sr[t]][sc[t]], st[t]);
  }
  __syncthreads();
  int cur = 0;
  for (int nt = 0; nt < 9; ++nt) {
    int nbase = nt * 64;
    bf16v8 st[3];
    if (nt < 8) {
      #pragma unroll
      for (int t = 0; t < 3; ++t)
        st[t] = ld8(wq + (size_t)(nbase + 64 + sr[t]) * C_ + sc[t]);
    }
    f32x4 acc[2][4];
    #pragma unroll
    for (int rt = 0; rt < 2; ++rt)
      #pragma unroll
      for (int s = 0; s < 4; ++s) acc[rt][s] = (f32x4){0.f, 0.f, 0.f, 0.f};
    #pragma unroll
    for (int s = 0; s < 4; ++s)
      #pragma unroll
      for (int kk = 0; kk < 6; ++kk) {
        bf16v8 bb = ld8(&bbuf[cur][s * 16 + lr][kk * 32 + lk]);
        acc[0][s] = __builtin_amdgcn_mfma_f32_16x16x32_bf16(a[0][kk], bb, acc[0][s], 0, 0, 0);
        acc[1][s] = __builtin_amdgcn_mfma_f32_16x16x32_bf16(a[1][kk], bb, acc[1][s], 0, 0, 0);
      }
    #pragma unroll
    for (int s = 0; s < 4; ++s) {
      int ncol = nbase + s * 16 + lr;
      float bias = qkvb[ncol];
      int sec = ncol / 192, cm = ncol - sec * 192;
      int head = cm >> 5, dd = cm & 31;
      float mul = (sec == 0) ? 0.17677669529663687f : 1.0f;  // fold q scale
      ushort_t* dst = sec == 0 ? q : (sec == 1 ? k : v);
      #pragma unroll
      for (int rt = 0; rt < 2; ++rt)
        #pragma unroll
        for (int i = 0; i < 4; ++i) {
          int gg = mbase + rt * 16 + lg * 4 + i;
          int win = gg / 49, tok = gg - win * 49;
          dst[((size_t)(win * 6 + head) * 49 + tok) * 32 + dd] = f2bf((acc[rt][s][i] + bias) * mul);
        }
    }
    if (nt < 8) {
      #pragma unroll
      for (int t = 0; t < 3; ++t) st8(&bbuf[cur ^ 1][sr[t]][sc[t]], st[t]);
    }
    __syncthreads();
    cur ^= 1;
  }
}

// ---- MFMA attention: block per window, 4 waves (16-row M-tiles), 6-head loop ----
__global__ __launch_bounds__(256, 4) void k_attn(const ushort_t* __restrict__ q,
                                                 const ushort_t* __restrict__ k,
                                                 const ushort_t* __restrict__ v,
                                                 const float* __restrict__ rpb,
                                                 const int* __restrict__ relidx,
                                                 const float* __restrict__ amask,
                                                 ushort_t* __restrict__ aout) {
  __shared__ ushort_t qs[2][64][40];   // stride 80B (16B-aligned, spreads banks)
  __shared__ ushort_t ks[2][64][40];
  __shared__ ushort_t vt[2][32][72];   // V^T: [d][tok], stride 144B
  __shared__ ushort_t pb[64][72];      // P (unnormalized exp), [qr][kc]
  int tid = threadIdx.x, wave = tid >> 6, lane = tid & 63;
  int lr = lane & 15, lg = lane >> 4, lk = lg * 8;
  int win = blockIdx.x, nw = win & 63;

  // zero pad regions once (rows 49..63 of qs/ks, cols 49..63 of vt)
  #pragma unroll
  for (int bb = 0; bb < 2; ++bb) {
    for (int z = tid; z < 15 * 40; z += 256) {
      qs[bb][49 + z / 40][z % 40] = 0;
      ks[bb][49 + z / 40][z % 40] = 0;
    }
    for (int z = tid; z < 32 * 15; z += 256) vt[bb][z / 15][49 + z % 15] = 0;
  }

  // stage-index (valid for tid < 196)
  int srow = tid >> 2, sc8 = (tid & 3) * 8;

  // precompute bias indices + mask values for this lane's 16 S elements
  int qrb = wave * 16 + lg * 4;
  int ridx6[4][4]; float mv[4][4]; bool cv[4], rv[4];
  #pragma unroll
  for (int i = 0; i < 4; ++i) rv[i] = (qrb + i) < 49;
  #pragma unroll
  for (int nt = 0; nt < 4; ++nt) {
    int kc = nt * 16 + lr;
    cv[nt] = kc < 49;
    #pragma unroll
    for (int i = 0; i < 4; ++i) {
      int qr = qrb + i;
      bool val = cv[nt] && (qr < 49);
      int p = val ? qr * 49 + kc : 0;
      ridx6[nt][i] = relidx[p] * 6;
      mv[nt][i] = val ? amask[(size_t)nw * 2401 + p] : 0.f;
    }
  }

  // prologue: stage head 0 into buf 0
  if (tid < 196) {
    size_t base = (size_t)win * 6 * 1568 + srow * 32 + sc8;
    st8(&qs[0][srow][sc8], ld8(q + base));
    st8(&ks[0][srow][sc8], ld8(k + base));
    u16v8 vv = *(const u16v8*)(v + base);
    #pragma unroll
    for (int j = 0; j < 8; ++j) vt[0][sc8 + j][srow] = vv[j];
  }
  __syncthreads();

  int cur = 0;
  #pragma unroll 1
  for (int h = 0; h < 6; ++h) {
    // issue next head's staging loads early
    u16v8 sq, sk, sv;
    if (h < 5 && tid < 196) {
      size_t base = ((size_t)win * 6 + h + 1) * 1568 + srow * 32 + sc8;
      sq = *(const u16v8*)(q + base);
      sk = *(const u16v8*)(k + base);
      sv = *(const u16v8*)(v + base);
    }
    // ---- QK^T: 4 MFMAs ----
    bf16v8 aq = ld8(&qs[cur][wave * 16 + lr][lk]);
    f32x4 accS[4];
    #pragma unroll
    for (int nt = 0; nt < 4; ++nt) {
      bf16v8 bk = ld8(&ks[cur][nt * 16 + lr][lk]);
      accS[nt] = __builtin_amdgcn_mfma_f32_16x16x32_bf16(aq, bk, (f32x4){0.f, 0.f, 0.f, 0.f}, 0, 0, 0);
    }
    // ---- S = acc + bias + mask; in-register softmax over rows ----
    float sv2[4][4];
    float mx[4] = {-3e38f, -3e38f, -3e38f, -3e38f};
    #pragma unroll
    for (int nt = 0; nt < 4; ++nt)
      #pragma unroll
      for (int i = 0; i < 4; ++i) {
        float s = accS[nt][i] + rpb[ridx6[nt][i] + h] + mv[nt][i];
        s = cv[nt] ? s : -3e38f;
        sv2[nt][i] = s;
        mx[i] = fmaxf(mx[i], s);
      }
    #pragma unroll
    for (int o = 1; o < 16; o <<= 1)
      #pragma unroll
      for (int i = 0; i < 4; ++i) mx[i] = fmaxf(mx[i], __shfl_xor(mx[i], o));
    float sm[4] = {0.f, 0.f, 0.f, 0.f};
    #pragma unroll
    for (int nt = 0; nt < 4; ++nt)
      #pragma unroll
      for (int i = 0; i < 4; ++i) {
        float e = __expf(sv2[nt][i] - mx[i]);
        sv2[nt][i] = e;
        sm[i] += e;
      }
    #pragma unroll
    for (int o = 1; o < 16; o <<= 1)
      #pragma unroll
      for (int i = 0; i < 4; ++i) sm[i] += __shfl_xor(sm[i], o);
    float rinv[4];
    #pragma unroll
    for (int i = 0; i < 4; ++i) rinv[i] = __builtin_amdgcn_rcpf(sm[i]);
    // write unnormalized P to LDS (own wave's rows only)
    #pragma unroll
    for (int nt = 0; nt < 4; ++nt)
      #pragma unroll
      for (int i = 0; i < 4; ++i)
        pb[qrb + i][nt * 16 + lr] = f2bf(sv2[nt][i]);
    // ---- PV: 4 MFMAs (K=64 in 2 steps) ----
    bf16v8 ap0 = ld8(&pb[wave * 16 + lr][lk]);
    bf16v8 ap1 = ld8(&pb[wave * 16 + lr][32 + lk]);
    #pragma unroll
    for (int nt2 = 0; nt2 < 2; ++nt2) {
      bf16v8 bv0 = ld8(&vt[cur][nt2 * 16 + lr][lk]);
      bf16v8 bv1 = ld8(&vt[cur][nt2 * 16 + lr][32 + lk]);
      f32x4 accO = __builtin_amdgcn_mfma_f32_16x16x32_bf16(ap0, bv0, (f32x4){0.f, 0.f, 0.f, 0.f}, 0, 0, 0);
      accO = __builtin_amdgcn_mfma_f32_16x16x32_bf16(ap1, bv1, accO, 0, 0, 0);
      #pragma unroll
      for (int i = 0; i < 4; ++i) {
        if (rv[i]) {
          int qr = qrb + i;
          aout[((size_t)win * 49 + qr) * C_ + h * 32 + nt2 * 16 + lr] = f2bf(accO[i] * rinv[i]);
        }
      }
    }
    // ---- write next head's stage into other buffer ----
    if (h < 5 && tid < 196) {
      st8(&qs[cur ^ 1][srow][sc8], *(bf16v8*)&sq);
      st8(&ks[cur ^ 1][srow][sc8], *(bf16v8*)&sk);
      #pragma unroll
      for (int j = 0; j < 8; ++j) vt[cur ^ 1][sc8 + j][srow] = sv[j];
    }
    __syncthreads();
    cur ^= 1;
  }
}

// ---- proj GEMM (staged-B) + reverse window/roll scatter + residual -> d_out ----
__global__ __launch_bounds__(512, 4) void k_proj(const ushort_t* __restrict__ ain,
                                                 const ushort_t* __restrict__ wp,
                                                 const float* __restrict__ pb,
                                                 const float* __restrict__ x0,
                                                 float* __restrict__ x2) {
  __shared__ ushort_t bbuf[2][64][200];
  int tid = threadIdx.x, wave = tid >> 6, lane = tid & 63;
  int lr = lane & 15, lg = lane >> 4, lk = lg * 8;
  int mbase = blockIdx.x * 256 + wave * 32;
  bf16v8 a[2][6];
  #pragma unroll
  for (int rt = 0; rt < 2; ++rt)
    #pragma unroll
    for (int kk = 0; kk < 6; ++kk)
      a[rt][kk] = ld8(ain + (size_t)(mbase + rt * 16 + lr) * C_ + kk * 32 + lk);
  int se[3], sr[3], sc[3];
  #pragma unroll
  for (int t = 0; t < 3; ++t) {
    se[t] = (tid + t * 512) * 8; sr[t] = se[t] / 192; sc[t] = se[t] - sr[t] * 192;
  }
  {
    bf16v8 st[3];
    #pragma unroll
    for (int t = 0; t < 3; ++t) st[t] = ld8(wp + (size_t)sr[t] * C_ + sc[t]);
    #pragma unroll
    for (int t = 0; t < 3; ++t) st8(&bbuf[0][sr[t]][sc[t]], st[t]);
  }
  __syncthreads();
  int cur = 0;
  for (int nt = 0; nt < 3; ++nt) {
    int nbase = nt * 64;
    bf16v8 st[3];
    if (nt < 2) {
      #pragma unroll
      for (int t = 0; t < 3; ++t)
        st[t] = ld8(wp + (size_t)(nbase + 64 + sr[t]) * C_ + sc[t]);
    }
    f32x4 acc[2][4];
    #pragma unroll
    for (int rt = 0; rt < 2; ++rt)
      #pragma unroll
      for (int s = 0; s < 4; ++s) acc[rt][s] = (f32x4){0.f, 0.f, 0.f, 0.f};
    #pragma unroll
    for (int s = 0; s < 4; ++s)
      #pragma unroll
      for (int kk = 0; kk < 6; ++kk) {
        bf16v8 bb = ld8(&bbuf[cur][s * 16 + lr][kk * 32 + lk]);
        acc[0][s] = __builtin_amdgcn_mfma_f32_16x16x32_bf16(a[0][kk], bb, acc[0][s], 0, 0, 0);
        acc[1][s] = __builtin_amdgcn_mfma_f32_16x16x32_bf16(a[1][kk], bb, acc[1][s], 0, 0, 0);
      }
    #pragma unroll
    for (int s = 0; s < 4; ++s) {
      int ncol = nbase + s * 16 + lr;
      float bias = pb[ncol];
      #pragma unroll
      for (int rt = 0; rt < 2; ++rt)
        #pragma unroll
        for (int i = 0; i < 4; ++i) {
          int gg = mbase + rt * 16 + lg * 4 + i;
          int win = gg / 49, tok = gg - win * 49;
          int bb2 = win >> 6, nw = win & 63;
          int wr = nw >> 3, wc = nw & 7;
          int ii = tok / 7, jj = tok - ii * 7;
          int hh = wr * 7 + ii + SHIFT_; if (hh >= HW_) hh -= HW_;
          int ww = wc * 7 + jj + SHIFT_; if (ww >= HW_) ww -= HW_;
          size_t dst = ((size_t)bb2 * 3136 + hh * 56 + ww) * C_ + ncol;
          x2[dst] = x0[dst] + acc[rt][s][i] + bias;
        }
    }
    if (nt < 2) {
      #pragma unroll
      for (int t = 0; t < 3; ++t) st8(&bbuf[cur ^ 1][sr[t]][sc[t]], st[t]);
    }
    __syncthreads();
    cur ^= 1;
  }
}

// ---- LN2: x2 (d_out) -> y2 bf16 ----
__global__ __launch_bounds__(256) void k_ln2(const float* __restrict__ x2,
                                             const float* __restrict__ g,
                                             const float* __restrict__ b,
                                             ushort_t* __restrict__ y2) {
  int wave = threadIdx.x >> 6, lane = threadIdx.x & 63;
  int gtok = blockIdx.x * 4 + wave;
  const float* row = x2 + (size_t)gtok * C_;
  float vals[3]; float s = 0.f, s2 = 0.f;
  #pragma unroll
  for (int r = 0; r < 3; ++r) { float t = row[lane + 64 * r]; vals[r] = t; s += t; s2 += t * t; }
  #pragma unroll
  for (int o = 32; o; o >>= 1) { s += __shfl_xor(s, o); s2 += __shfl_xor(s2, o); }
  float mean = s * (1.f / 192.f);
  float var  = s2 * (1.f / 192.f) - mean * mean;
  float rstd = rsqrtf(var + 1e-5f);
  ushort_t* orow = y2 + (size_t)gtok * C_;
  #pragma unroll
  for (int r = 0; r < 3; ++r) {
    int c = lane + 64 * r;
    orow[c] = f2bf((vals[r] - mean) * rstd * g[c] + b[c]);
  }
}

// ---- fused MLP (staged weights, dbuf, 1 barrier/chunk) ----
__global__ __launch_bounds__(512, 2) void k_mlp(const ushort_t* __restrict__ y2,
                                                const ushort_t* __restrict__ w1,
                                                const float* __restrict__ b1,
                                                const ushort_t* __restrict__ w2,
                                                const float* __restrict__ b2,
                                                float* __restrict__ out) {
  __shared__ ushort_t w1buf[2][64][200];
  __shared__ ushort_t w2buf[2][192][72];
  __shared__ ushort_t hbuf[8][32][40];
  int tid = threadIdx.x, wave = tid >> 6, lane = tid & 63;
  int lr = lane & 15, lg = lane >> 4, lk = lg * 8;
  int mrow = blockIdx.x * 256 + wave * 32;

  int e1[3], r1[3], c1[3], e2[3], r2[3], c2[3];
  #pragma unroll
  for (int t = 0; t < 3; ++t) {
    e1[t] = (tid + t * 512) * 8; r1[t] = e1[t] / 192; c1[t] = e1[t] - r1[t] * 192;
    e2[t] = (tid + t * 512) * 8; r2[t] = e2[t] / 64;  c2[t] = e2[t] - r2[t] * 64;
  }

  bf16v8 a1[2][6];
  #pragma unroll
  for (int rt = 0; rt < 2; ++rt)
    #pragma unroll
    for (int kk = 0; kk < 6; ++kk)
      a1[rt][kk] = ld8(y2 + (size_t)(mrow + rt * 16 + lr) * C_ + kk * 32 + lk);

  f32x4 acc2[2][12];
  #pragma unroll
  for (int rt = 0; rt < 2; ++rt)
    #pragma unroll
    for (int nc = 0; nc < 12; ++nc)
      acc2[rt][nc] = (f32x4){0.f, 0.f, 0.f, 0.f};

  {
    bf16v8 s1v[3], s2v[3];
    #pragma unroll
    for (int t = 0; t < 3; ++t) {
      s1v[t] = ld8(w1 + (size_t)r1[t] * C_ + c1[t]);
      s2v[t] = ld8(w2 + (size_t)r2[t] * HID_ + c2[t]);
    }
    #pragma unroll
    for (int t = 0; t < 3; ++t) {
      st8(&w1buf[0][r1[t]][c1[t]], s1v[t]);
      st8(&w2buf[0][r2[t]][c2[t]], s2v[t]);
    }
  }
  __syncthreads();
  int cur = 0;

  #pragma unroll 1
  for (int ch = 0; ch < 12; ++ch) {
    bf16v8 s1v[3], s2v[3];
    if (ch < 11) {
      #pragma unroll
      for (int t = 0; t < 3; ++t) {
        s1v[t] = ld8(w1 + (size_t)((ch + 1) * 64 + r1[t]) * C_ + c1[t]);
        s2v[t] = ld8(w2 + (size_t)r2[t] * HID_ + (ch + 1) * 64 + c2[t]);
      }
    }
    f32x4 acc1[2][4];
    #pragma unroll
    for (int rt = 0; rt < 2; ++rt)
      #pragma unroll
      for (int nt = 0; nt < 4; ++nt) acc1[rt][nt] = (f32x4){0.f, 0.f, 0.f, 0.f};
    #pragma unroll
    for (int nt = 0; nt < 4; ++nt)
      #pragma unroll
      for (int kk = 0; kk < 6; ++kk) {
        bf16v8 bb = ld8(&w1buf[cur][nt * 16 + lr][kk * 32 + lk]);
        acc1[0][nt] = __builtin_amdgcn_mfma_f32_16x16x32_bf16(a1[0][kk], bb, acc1[0][nt], 0, 0, 0);
        acc1[1][nt] = __builtin_amdgcn_mfma_f32_16x16x32_bf16(a1[1][kk], bb, acc1[1][nt], 0, 0, 0);
      }
    float bs[4];
    #pragma unroll
    for (int nt = 0; nt < 4; ++nt) bs[nt] = b1[ch * 64 + nt * 16 + lr];
    #pragma unroll
    for (int hf = 0; hf < 2; ++hf) {
      #pragma unroll
      for (int rt = 0; rt < 2; ++rt)
        #pragma unroll
        for (int nt2 = 0; nt2 < 2; ++nt2) {
          int nt = hf * 2 + nt2;
          #pragma unroll
          for (int i = 0; i < 4; ++i) {
            int row = rt * 16 + lg * 4 + i;
            hbuf[wave][row][nt2 * 16 + lr] = f2bf(gelu_f(acc1[rt][nt][i] + bs[nt]));
          }
        }
      bf16v8 a2[2];
      #pragma unroll
      for (int rt = 0; rt < 2; ++rt)
        a2[rt] = ld8(&hbuf[wave][rt * 16 + lr][lk]);
      #pragma unroll
      for (int nc = 0; nc < 12; ++nc) {
        bf16v8 bb = ld8(&w2buf[cur][nc * 16 + lr][hf * 32 + lk]);
        acc2[0][nc] = __builtin_amdgcn_mfma_f32_16x16x32_bf16(a2[0], bb, acc2[0][nc], 0, 0, 0);
        acc2[1][nc] = __builtin_amdgcn_mfma_f32_16x16x32_bf16(a2[1], bb, acc2[1][nc], 0, 0, 0);
      }
    }
    if (ch < 11) {
      #pragma unroll
      for (int t = 0; t < 3; ++t) {
        st8(&w1buf[cur ^ 1][r1[t]][c1[t]], s1v[t]);
        st8(&w2buf[cur ^ 1][r2[t]][c2[t]], s2v[t]);
      }
    }
    __syncthreads();
    cur ^= 1;
  }
  #pragma unroll
  for (int nc = 0; nc < 12; ++nc) {
    float bias = b2[nc * 16 + lr];
    #pragma unroll
    for (int rt = 0; rt < 2; ++rt)
      #pragma unroll
      for (int i = 0; i < 4; ++i) {
        size_t o = (size_t)(mrow + rt * 16 + lg * 4 + i) * C_ + nc * 16 + lr;
        out[o] = out[o] + acc2[rt][nc][i] + bias;
      }
  }
}

extern "C" void kernel_launch(void* const* d_in, const int* in_sizes, int n_in,
                              void* d_out, int out_size, void* d_ws, size_t ws_size,
                              hipStream_t stream) {
  const float* x     = (const float*)d_in[0];
  const float* n1g   = (const float*)d_in[1];
  const float* n1b   = (const float*)d_in[2];
  const float* qkvw  = (const float*)d_in[3];
  const float* qkvb  = (const float*)d_in[4];
  const float* rpb   = (const float*)d_in[5];
  const float* projw = (const float*)d_in[6];
  const float* projb = (const float*)d_in[7];
  const float* n2g   = (const float*)d_in[8];
  const float* n2b   = (const float*)d_in[9];
  const float* fc1w  = (const float*)d_in[10];
  const float* fc1b  = (const float*)d_in[11];
  const float* fc2w  = (const float*)d_in[12];
  const float* fc2b  = (const float*)d_in[13];
  const int*   relidx= (const int*)d_in[14];
  const float* amask = (const float*)d_in[15];
  float* out = (float*)d_out;

  const size_t MC = (size_t)M_ * C_;
  ushort_t* ws = (ushort_t*)d_ws;
  ushort_t* xw = ws;                 // (M,192) bf16; later reused as attn_out
  ushort_t* q  = ws + MC;            // (nwin,heads,tok,hd); later reused as y2
  ushort_t* k  = ws + 2 * MC;
  ushort_t* v  = ws + 3 * MC;
  ushort_t* wq = ws + 4 * MC;
  ushort_t* wp = wq + (size_t)C3_ * C_;
  ushort_t* w1 = wp + (size_t)C_ * C_;
  ushort_t* w2 = w1 + (size_t)HID_ * C_;

  int n0 = C3_ * C_, n1 = C_ * C_, n2 = HID_ * C_, n3 = C_ * HID_;
  k_f2b4<<<(n0 + n1 + n2 + n3 + 255) / 256, 256, 0, stream>>>(
      qkvw, wq, n0, projw, wp, n1, fc1w, w1, n2, fc2w, w2, n3);

  k_ln1<<<M_ / 4, 256, 0, stream>>>(x, n1g, n1b, xw);
  k_qkv<<<M_ / 256, 512, 0, stream>>>(xw, wq, qkvb, q, k, v);
  k_attn<<<NWIN_, 256, 0, stream>>>(q, k, v, rpb, relidx, amask, xw);
  k_proj<<<M_ / 256, 512, 0, stream>>>(xw, wp, projb, x, out);
  k_ln2<<<M_ / 4, 256, 0, stream>>>(out, n2g, n2b, q);
  k_mlp<<<M_ / 256, 512, 0, stream>>>(q, w1, fc1b, w2, fc2b, out);
}